// Round 8
// baseline (218.668 us; speedup 1.0000x reference)
//
#include <hip/hip_runtime.h>

#define NB 256
#define NPER 128
#define NN 32768
#define DEG 8
#define EREAL (NN*DEG)
#define HH 32
#define NHEADS 2
#define WLEN 7
#define RSQRT_H 0.17677669529663687f

#define FRONT_LDS 136208
#define WALK2_LDS 147712

// swizzled index for [128][128] f32 matrix: row n, elem v.
// float4-chunk q = v>>2 stored at q^(n&31) -> rows coalesced, columns conflict-free.
__device__ __forceinline__ int sidx8(int n, int v){
    return n*128 + ((((v>>2) ^ (n&31))<<2) | (v&3));
}

// ============ K1: fused embed + 3xGCN + QK projections + attention ============
__global__ __launch_bounds__(1024) void k_front(
    const float* __restrict__ z_table, const int* __restrict__ z,
    const float* __restrict__ convW, const float* __restrict__ convb,
    const float* __restrict__ k1W, const float* __restrict__ k1b,
    const float* __restrict__ q1W, const float* __restrict__ q1b,
    const float* __restrict__ k2W, const float* __restrict__ k2b,
    const float* __restrict__ q2W, const float* __restrict__ q2b,
    const int* __restrict__ erow, const int* __restrict__ node_i, const int* __restrict__ node_j,
    float2* __restrict__ wp8, float* __restrict__ rat_g,
    float* __restrict__ exw_g, float* __restrict__ omega_g)
{
    extern __shared__ char sm[];
    float* xl   = (float*)sm;               // [128][32]
    float* t1   = (float*)(sm + 16384);
    float* t2   = (float*)(sm + 32768);
    float* Wb   = (float*)(sm + 49152);     // 4096 floats staging (warr overlay)
    float* rowf = (float*)(sm + 65536);     // [128][64] q-proj (chunk-swizzled)
    float* colf = (float*)(sm + 98304);     // [128][64] k-proj (chunk-swizzled)
    int*   rows = (int*)(sm + 131072);      // [128][8]
    float* dinv = (float*)(sm + 135168);
    float* bias = (float*)(sm + 135680);
    float* omg  = (float*)(sm + 136192);

    int b = blockIdx.x, tid = threadIdx.x;
    int iloc = node_i[b] & 127, jloc = node_j[b] & 127;

    #pragma unroll
    for (int ii=0;ii<4;ii++){
        int i = tid + ii*1024;
        int n = i>>5, d = i&31;
        xl[i] = z_table[z[b*128+n]*32 + d];
    }
    rows[(tid&127)*8 + (tid>>7)] = erow[b*1024 + tid] & 127;
    if (tid < 128) dinv[tid] = rsqrtf((tid==iloc||tid==jloc)? 10.f : 9.f);

    int j = tid & 31, rg = tid>>5;
    for (int l=0;l<3;l++){
        __syncthreads();
        Wb[tid] = convW[l*1024+tid];
        if (tid<32) bias[tid] = convb[l*32+tid];
        __syncthreads();
        float Wc[32];
        #pragma unroll
        for (int k=0;k<32;k++) Wc[k] = Wb[k*32+j];
        #pragma unroll
        for (int ii=0;ii<4;ii++){
            int r = rg + 32*ii;
            const float4* xr = (const float4*)&xl[r*32];
            float a = 0.f;
            #pragma unroll
            for (int k4=0;k4<8;k4++){
                float4 xv = xr[k4];
                a += xv.x*Wc[4*k4] + xv.y*Wc[4*k4+1] + xv.z*Wc[4*k4+2] + xv.w*Wc[4*k4+3];
            }
            t1[r*32+j] = a;
        }
        __syncthreads();
        #pragma unroll
        for (int ii=0;ii<4;ii++){
            int c = rg + 32*ii;
            float acc = dinv[c]*t1[c*32+j];
            #pragma unroll
            for (int s=0;s<8;s++){
                int r = rows[c*8+s];
                acc += dinv[r]*t1[r*32+j];
            }
            if (c==iloc) acc += dinv[jloc]*t1[jloc*32+j];
            if (c==jloc) acc += dinv[iloc]*t1[iloc*32+j];
            float v = dinv[c]*acc + bias[j];
            if (l<2) v = fmaxf(v,0.f);
            xl[c*32+j] = v;
        }
    }
    __syncthreads();
    for (int i=tid;i<2048;i+=1024) Wb[i] = (i<1024)? k1W[i] : q1W[i-1024];
    if (tid<64) bias[tid] = (tid<32)? k1b[tid] : q1b[tid-32];
    __syncthreads();
    {
        float Wa[32], Wq[32];
        #pragma unroll
        for (int k=0;k<32;k++){ Wa[k] = Wb[k*32+j]; Wq[k] = Wb[1024 + k*32+j]; }
        #pragma unroll
        for (int ii=0;ii<4;ii++){
            int n = rg + 32*ii;
            const float4* xr = (const float4*)&xl[n*32];
            float a1 = bias[j], a2 = bias[32+j];
            #pragma unroll
            for (int k4=0;k4<8;k4++){
                float4 xv = xr[k4];
                a1 += xv.x*Wa[4*k4] + xv.y*Wa[4*k4+1] + xv.z*Wa[4*k4+2] + xv.w*Wa[4*k4+3];
                a2 += xv.x*Wq[4*k4] + xv.y*Wq[4*k4+1] + xv.z*Wq[4*k4+2] + xv.w*Wq[4*k4+3];
            }
            t1[n*32+j] = a1>0.f? a1 : 0.2f*a1;
            t2[n*32+j] = a2>0.f? a2 : 0.2f*a2;
        }
    }
    __syncthreads();
    for (int i=tid;i<4096;i+=1024) Wb[i] = (i<2048)? k2W[i] : q2W[i-2048];
    if (tid<128) bias[tid] = (tid<64)? k2b[tid] : q2b[tid-64];
    __syncthreads();
    {
        int j2 = tid & 63, rg2 = tid>>6;
        float Wk[32], Wq[32];
        #pragma unroll
        for (int k=0;k<32;k++){ Wk[k] = Wb[k*64+j2]; Wq[k] = Wb[2048 + k*64+j2]; }
        #pragma unroll
        for (int ii=0;ii<8;ii++){
            int n = rg2 + 16*ii;
            const float4* u4 = (const float4*)&t1[n*32];
            const float4* v4 = (const float4*)&t2[n*32];
            float o1 = bias[j2], o2 = bias[64+j2];
            #pragma unroll
            for (int k4=0;k4<8;k4++){
                float4 u = u4[k4], v = v4[k4];
                o1 += u.x*Wk[4*k4] + u.y*Wk[4*k4+1] + u.z*Wk[4*k4+2] + u.w*Wk[4*k4+3];
                o2 += v.x*Wq[4*k4] + v.y*Wq[4*k4+1] + v.z*Wq[4*k4+2] + v.w*Wq[4*k4+3];
            }
            int sidx = n*64 + ((((j2>>2) ^ (n&7)) << 2) | (j2&3));
            rowf[sidx] = o1;
            colf[sidx] = o2;
        }
    }
    float* warr = Wb;
    __syncthreads();
    {
        int c = tid & 127, h = (tid>>7)&1, sgrp = tid>>8;
        int cs = c&7, h8 = h*8;
        const float4* cf = (const float4*)&colf[c*64];
        float4 kv[8];
        #pragma unroll
        for (int k4=0;k4<8;k4++) kv[k4] = cf[h8 + (k4^cs)];
        #pragma unroll
        for (int si=0;si<2;si++){
            int s = sgrp*2+si;
            int r = rows[c*8+s];
            int rs = r&7;
            const float4* rf = (const float4*)&rowf[r*64];
            float a = 0.f;
            #pragma unroll
            for (int k4=0;k4<8;k4++){
                float4 q = rf[h8 + (k4^rs)];
                a += q.x*kv[k4].x + q.y*kv[k4].y + q.z*kv[k4].z + q.w*kv[k4].w;
            }
            warr[(h*128+c)*9+s] = a*RSQRT_H;
        }
        if (sgrp==0){
            int r = -1;
            if (c==jloc) r = iloc; else if (c==iloc) r = jloc;
            float a = -3.0e38f;
            if (r>=0){
                int rs = r&7;
                const float4* rf = (const float4*)&rowf[r*64];
                a = 0.f;
                #pragma unroll
                for (int k4=0;k4<8;k4++){
                    float4 q = rf[h8 + (k4^rs)];
                    a += q.x*kv[k4].x + q.y*kv[k4].y + q.z*kv[k4].z + q.w*kv[k4].w;
                }
                a *= RSQRT_H;
            }
            warr[(h*128+c)*9+8] = a;
        }
    }
    __syncthreads();
    if (tid < 256){
        int c = tid & 127, h = tid >> 7;
        float wv[9];
        #pragma unroll
        for (int s=0;s<9;s++) wv[s] = warr[(h*128+c)*9+s];
        float wmax = wv[0];
        #pragma unroll
        for (int s=1;s<9;s++) wmax = fmaxf(wmax, wv[s]);
        float e[9]; float sp = 0.f;
        #pragma unroll
        for (int s=0;s<9;s++){ e[s] = expf(wv[s]-wmax); sp += e[s]; }
        float sm_ = sp - e[8];
        float rp = 1.f/(sp+1e-16f);
        float rat = (sp+1e-16f)/(sm_+1e-16f);
        size_t base = ((size_t)h*NN + b*128 + c)*8;
        #pragma unroll
        for (int s=0;s<8;s++)
            wp8[base+s] = make_float2(e[s]*rp, __int_as_float(rows[c*8+s]));  // raw row idx
        rat_g[h*NN + b*128 + c] = rat;
        if (c==jloc || c==iloc){
            int k = (c==jloc)? 0 : 1;
            exw_g[(b*2+h)*2 + k] = e[8]*rp;
            omg[h*2+k] = 1.f/(1.f+expf(-wv[8]));
        }
    }
    __syncthreads();
    if (tid < 2) omega_g[b*2+tid] = omg[tid*2] + omg[tid*2+1];
}

// ============ K2: walk via A^2..A^4 + trace identities, 1 block per (b,h,sg) ============
// Register-resident edge weights for the mults (no LDS wr reads in hot loop);
// transposed SoA (cwT/crT) for wave-0 column propagation (2 lanes/bank = free).
__global__ __launch_bounds__(1024, 4) void k_walk(
    const float2* __restrict__ wp8, const float* __restrict__ rat_g,
    const float* __restrict__ exw_g,
    const int* __restrict__ node_i, const int* __restrict__ node_j,
    float* __restrict__ featbuf)
{
    extern __shared__ char sm[];
    float*  PX = (float*)sm;                 // 64KB
    float*  PY = (float*)(sm + 65536);       // 64KB
    float2* wr = (float2*)(sm + 131072);     // [128][8] (w, row idx) 8KB
    float*  cwT= (float*)(sm + 139264);      // [8][128] weights transposed 4KB
    int*    crT= (int*)  (sm + 143360);      // [8][128] rows transposed 4KB
    float*  scr= (float*)(sm + 147456);      // 64 floats
    int bid = blockIdx.x;
    int b = bid>>2, h = (bid>>1)&1, sg = bid&1;
    int tid = threadIdx.x;

    {   float2 p = wp8[((size_t)h*NN + b*128)*8 + tid];
        if (sg) p.x *= rat_g[h*NN + b*128 + (tid>>3)];
        wr[tid] = p;
        cwT[(tid&7)*128 + (tid>>3)] = p.x;
        crT[(tid&7)*128 + (tid>>3)] = __float_as_int(p.y);
    }
    int iloc = node_i[b]&127, jloc = node_j[b]&127;
    float exw0=0.f, exw1=0.f; int exc0=-1, exc1=-1;
    if (!sg){
        exw0 = exw_g[(b*2+h)*2+0];
        exw1 = exw_g[(b*2+h)*2+1];
        exc0 = jloc; exc1 = iloc;
    }
    {   float4* PX4 = (float4*)PX;
        #pragma unroll
        for (int k=0;k<4;k++) PX4[tid + k*1024] = make_float4(0.f,0.f,0.f,0.f);
    }
    __syncthreads();
    // ---- build A^1 into PX (waves 1-2: rows 0..127; wave 0 freed for propagation) ----
    if (tid >= 64 && tid < 192){
        int c = tid - 64;
        #pragma unroll
        for (int s=0;s<8;s++){
            float2 p = wr[c*8+s];
            PX[sidx8(c, __float_as_int(p.y))] += p.x;
        }
        if (c==exc0) PX[sidx8(c, iloc)] += exw0;
        if (c==exc1) PX[sidx8(c, jloc)] += exw1;
    }
    // ---- column propagation (wave 0, register-resident weights, no barriers) ----
    if (tid < 64){
        int l = tid;
        float w0r[8], w1r[8]; int r0r[8], r1r[8];
        #pragma unroll
        for (int s=0;s<8;s++){
            w0r[s] = cwT[s*128+l];    r0r[s] = crT[s*128+l];
            w1r[s] = cwT[s*128+64+l]; r1r[s] = crT[s*128+64+l];
        }
        float ci0 = (iloc==l)?1.f:0.f, ci1 = (iloc==64+l)?1.f:0.f;
        float cj0 = (jloc==l)?1.f:0.f, cj1 = (jloc==64+l)?1.f:0.f;
        int il = iloc&63, jl = jloc&63;
        for (int t=1;t<=9;t++){
            float a0 = __shfl(ci0, il), a1 = __shfl(ci1, il);
            float b0 = __shfl(cj0, il), b1 = __shfl(cj1, il);
            float c0 = __shfl(ci0, jl), c1 = __shfl(ci1, jl);
            float d0 = __shfl(cj0, jl), d1 = __shfl(cj1, jl);
            float vi_ci = (iloc<64)? a0:a1;   // ci[iloc]
            float vi_cj = (iloc<64)? b0:b1;   // cj[iloc]
            float vj_ci = (jloc<64)? c0:c1;   // ci[jloc]
            float vj_cj = (jloc<64)? d0:d1;   // cj[jloc]
            if (t>=3 && l==0){
                int tt = t-3;
                featbuf[((0*2+sg)*WLEN + tt)*(NHEADS*NB) + h*NB + b] = vi_ci + vj_cj; // nl
                featbuf[((1*2+sg)*WLEN + tt)*(NHEADS*NB) + h*NB + b] = vi_cj + vj_ci; // ll
            }
            if (t<=8){
                float nci0=0.f,ncj0=0.f,nci1=0.f,ncj1=0.f;
                #pragma unroll
                for (int s=0;s<8;s++){
                    int r0 = r0r[s];
                    float xlo = __shfl(ci0, r0&63), xhi = __shfl(ci1, r0&63);
                    float ylo = __shfl(cj0, r0&63), yhi = __shfl(cj1, r0&63);
                    nci0 += w0r[s] * ((r0<64)? xlo:xhi);
                    ncj0 += w0r[s] * ((r0<64)? ylo:yhi);
                    int r1 = r1r[s];
                    xlo = __shfl(ci0, r1&63); xhi = __shfl(ci1, r1&63);
                    ylo = __shfl(cj0, r1&63); yhi = __shfl(cj1, r1&63);
                    nci1 += w1r[s] * ((r1<64)? xlo:xhi);
                    ncj1 += w1r[s] * ((r1<64)? ylo:yhi);
                }
                if (exc0==l)    { nci0 += exw0*vi_ci; ncj0 += exw0*vi_cj; }
                if (exc0==64+l) { nci1 += exw0*vi_ci; ncj1 += exw0*vi_cj; }
                if (exc1==l)    { nci0 += exw1*vj_ci; ncj0 += exw1*vj_cj; }
                if (exc1==64+l) { nci1 += exw1*vj_ci; ncj1 += exw1*vj_cj; }
                ci0=nci0; ci1=nci1; cj0=ncj0; cj1=ncj1;
            }
        }
    }

    int c = tid>>3, j8 = tid&7, cx = c&31;
    // register-resident weights for the mults (group-uniform copies)
    float rwv[8]; int rof[8], rxv[8];
    #pragma unroll
    for (int s=0;s<8;s++){
        float2 p = wr[c*8+s];
        int r = __float_as_int(p.y);
        rwv[s] = p.x; rof[s] = r*32; rxv[s] = r&31;
    }
    __syncthreads();

    auto mult = [&](float* dst, const float* src){
        float4 a0={0,0,0,0}, a1={0,0,0,0}, a2={0,0,0,0}, a3={0,0,0,0};
        #pragma unroll
        for (int s=0;s<8;s++){
            float w = rwv[s];
            const float4* srow = (const float4*)src + rof[s];
            int rx = rxv[s];
            float4 v0=srow[(j8+ 0)^rx], v1=srow[(j8+ 8)^rx], v2=srow[(j8+16)^rx], v3=srow[(j8+24)^rx];
            a0.x+=w*v0.x; a0.y+=w*v0.y; a0.z+=w*v0.z; a0.w+=w*v0.w;
            a1.x+=w*v1.x; a1.y+=w*v1.y; a1.z+=w*v1.z; a1.w+=w*v1.w;
            a2.x+=w*v2.x; a2.y+=w*v2.y; a2.z+=w*v2.z; a2.w+=w*v2.w;
            a3.x+=w*v3.x; a3.y+=w*v3.y; a3.z+=w*v3.z; a3.w+=w*v3.w;
        }
        if (c==exc0){
            const float4* srow = (const float4*)src + iloc*32; int rx = iloc&31;
            float4 v0=srow[(j8+ 0)^rx], v1=srow[(j8+ 8)^rx], v2=srow[(j8+16)^rx], v3=srow[(j8+24)^rx];
            a0.x+=exw0*v0.x; a0.y+=exw0*v0.y; a0.z+=exw0*v0.z; a0.w+=exw0*v0.w;
            a1.x+=exw0*v1.x; a1.y+=exw0*v1.y; a1.z+=exw0*v1.z; a1.w+=exw0*v1.w;
            a2.x+=exw0*v2.x; a2.y+=exw0*v2.y; a2.z+=exw0*v2.z; a2.w+=exw0*v2.w;
            a3.x+=exw0*v3.x; a3.y+=exw0*v3.y; a3.z+=exw0*v3.z; a3.w+=exw0*v3.w;
        }
        if (c==exc1){
            const float4* srow = (const float4*)src + jloc*32; int rx = jloc&31;
            float4 v0=srow[(j8+ 0)^rx], v1=srow[(j8+ 8)^rx], v2=srow[(j8+16)^rx], v3=srow[(j8+24)^rx];
            a0.x+=exw1*v0.x; a0.y+=exw1*v0.y; a0.z+=exw1*v0.z; a0.w+=exw1*v0.w;
            a1.x+=exw1*v1.x; a1.y+=exw1*v1.y; a1.z+=exw1*v1.z; a1.w+=exw1*v1.w;
            a2.x+=exw1*v2.x; a2.y+=exw1*v2.y; a2.z+=exw1*v2.z; a2.w+=exw1*v2.w;
            a3.x+=exw1*v3.x; a3.y+=exw1*v3.y; a3.z+=exw1*v3.z; a3.w+=exw1*v3.w;
        }
        float4* drow = (float4*)dst + c*32;
        drow[(j8+ 0)^cx]=a0; drow[(j8+ 8)^cx]=a1; drow[(j8+16)^cx]=a2; drow[(j8+24)^cx]=a3;
    };
    auto wreduce = [](float v){
        #pragma unroll
        for (int o=32;o;o>>=1) v += __shfl_down(v,o);
        return v;
    };

    mult(PY, PX);                       // A^2
    __syncthreads();
    mult(PX, PY);                       // A^3 (overwrites A^1)
    if (tid<128){                       // tr2 = diag(A^2) concurrent (reads PY only)
        float d = wreduce(PY[sidx8(tid,tid)]);
        if ((tid&63)==0) scr[0+(tid>>6)] = d;
    }
    __syncthreads();
    mult(PY, PX);                       // A^4 (overwrites A^2)
    if (tid<128){                       // tr3 = diag(A^3)
        float d = wreduce(PX[sidx8(tid,tid)]);
        if ((tid&63)==0) scr[2+(tid>>6)] = d;
    }
    __syncthreads();
    // ---- tr4 diag, tr5 sparse, tr6/7/8 transpose pairs ----
    if (tid<128){
        float d = wreduce(PY[sidx8(tid,tid)]);
        if ((tid&63)==0) scr[4+(tid>>6)] = d;
        float s5 = 0.f;
        #pragma unroll
        for (int s=0;s<8;s++){
            float2 p = wr[tid*8+s];
            s5 += p.x * PY[sidx8(__float_as_int(p.y), tid)];
        }
        if (tid==exc0) s5 += exw0 * PY[sidx8(iloc, jloc)];
        if (tid==exc1) s5 += exw1 * PY[sidx8(jloc, iloc)];
        s5 = wreduce(s5);
        if ((tid&63)==0) scr[6+(tid>>6)] = s5;
    }
    {   // bank-fixed pair phase: lane j8 owns elements bb = j8+8m (m=0..15)
        float t6=0.f, t7=0.f, t8=0.f;
        #pragma unroll
        for (int m=0;m<16;m++){
            int bb = j8 + 8*m;
            int ai = sidx8(c, bb);
            int bi = sidx8(bb, c);
            float a3 = PX[ai], a4 = PY[ai];
            float b3 = PX[bi], b4 = PY[bi];
            t6 += a3*b3; t7 += a3*b4; t8 += a4*b4;
        }
        t6 = wreduce(t6); t7 = wreduce(t7); t8 = wreduce(t8);
        int w = tid>>6;
        if ((tid&63)==0){ scr[8+w]=t6; scr[24+w]=t7; scr[40+w]=t8; }
    }
    __syncthreads();
    if (tid==0){
        float tr2=scr[0]+scr[1], tr3=scr[2]+scr[3], tr4=scr[4]+scr[5], tr5=scr[6]+scr[7];
        float t6=0.f,t7=0.f,t8=0.f;
        #pragma unroll
        for (int w=0;w<16;w++){ t6+=scr[8+w]; t7+=scr[24+w]; t8+=scr[40+w]; }
        int gb = ((2*2+sg)*WLEN)*(NHEADS*NB) + h*NB + b;
        featbuf[gb+0*(NHEADS*NB)] = tr2;
        featbuf[gb+1*(NHEADS*NB)] = tr3;
        featbuf[gb+2*(NHEADS*NB)] = tr4;
        featbuf[gb+3*(NHEADS*NB)] = tr5;
        featbuf[gb+4*(NHEADS*NB)] = t6;
        featbuf[gb+5*(NHEADS*NB)] = t7;
        featbuf[gb+6*(NHEADS*NB)] = t8;
    }
}

// ============ K3: feature assembly + MLP ============
__global__ __launch_bounds__(256) void k_final(const float* __restrict__ W1, const float* __restrict__ b1,
                       const float* __restrict__ W2, const float* __restrict__ b2,
                       const float* __restrict__ featbuf, const float* __restrict__ omega,
                       float* __restrict__ out){
    __shared__ float sW1[72*HH];
    __shared__ float sb1[HH];
    __shared__ float sW2[HH];
    __shared__ float sb2;
    int tid = threadIdx.x;
    for (int i=tid;i<72*HH;i+=256) sW1[i] = W1[i];
    if (tid<HH){ sb1[tid]=b1[tid]; sW2[tid]=W2[tid]; }
    if (tid==0) sb2 = b2[0];
    __syncthreads();
    int b = tid;
    float h1[HH];
    #pragma unroll
    for (int j2=0;j2<HH;j2++) h1[j2] = sb1[j2];
    auto rd = [&](int idx){ return featbuf[idx]; };
    auto addf = [&](int fi, float v){
        #pragma unroll
        for (int j2=0;j2<HH;j2++) h1[j2] += v * sW1[fi*HH + j2];
    };
    for (int h2=0;h2<NHEADS;h2++)
        for (int t=0;t<WLEN;t++){
            float gp = rd(((2*2+0)*WLEN+t)*(NHEADS*NB)+h2*NB+b);
            float gm = rd(((2*2+1)*WLEN+t)*(NHEADS*NB)+h2*NB+b);
            addf(h2*WLEN+t, gp-gm);
        }
    for (int h2=0;h2<NHEADS;h2++) addf(14+h2, omega[b*NHEADS+h2]);
    for (int h2=0;h2<NHEADS;h2++)
        for (int t=0;t<WLEN;t++){
            addf(16+h2*WLEN+t, rd(((0*2+0)*WLEN+t)*(NHEADS*NB)+h2*NB+b));
            addf(30+h2*WLEN+t, rd(((0*2+1)*WLEN+t)*(NHEADS*NB)+h2*NB+b));
            addf(44+h2*WLEN+t, rd(((1*2+0)*WLEN+t)*(NHEADS*NB)+h2*NB+b));
            addf(58+h2*WLEN+t, rd(((1*2+1)*WLEN+t)*(NHEADS*NB)+h2*NB+b));
        }
    float o = sb2;
    #pragma unroll
    for (int j2=0;j2<HH;j2++) o += fmaxf(h1[j2],0.f)*sW2[j2];
    out[b] = o;
}

extern "C" void kernel_launch(void* const* d_in, const int* in_sizes, int n_in,
                              void* d_out, int out_size, void* d_ws, size_t ws_size,
                              hipStream_t stream){
    const float* z_table = (const float*)d_in[0];
    const float* convW   = (const float*)d_in[1];
    const float* convb   = (const float*)d_in[2];
    const float* k1W     = (const float*)d_in[3];
    const float* k1b     = (const float*)d_in[4];
    const float* q1W     = (const float*)d_in[5];
    const float* q1b     = (const float*)d_in[6];
    const float* k2W     = (const float*)d_in[7];
    const float* k2b     = (const float*)d_in[8];
    const float* q2W     = (const float*)d_in[9];
    const float* q2b     = (const float*)d_in[10];
    const float* mW1     = (const float*)d_in[11];
    const float* mb1     = (const float*)d_in[12];
    const float* mW2     = (const float*)d_in[13];
    const float* mb2     = (const float*)d_in[14];
    const int* z         = (const int*)d_in[15];
    const int* erow      = (const int*)d_in[16];
    const int* node_i    = (const int*)d_in[20];
    const int* node_j    = (const int*)d_in[21];
    float* out = (float*)d_out;

    char* ws = (char*)d_ws;
    size_t off = 0;
    auto alloc = [&](size_t bytes){ void* p = ws + off; off += (bytes + 255) & ~255ULL; return p; };
    float2* wp8     = (float2*)alloc((size_t)NHEADS*NN*8*8);
    float*  rat     = (float*) alloc((size_t)NHEADS*NN*4);
    float*  exw     = (float*) alloc((size_t)NB*NHEADS*2*4);
    float*  omega   = (float*) alloc((size_t)NB*NHEADS*4);
    float*  featbuf = (float*) alloc((size_t)3*2*WLEN*NHEADS*NB*4);

    hipFuncSetAttribute((const void*)k_front, hipFuncAttributeMaxDynamicSharedMemorySize, FRONT_LDS);
    hipFuncSetAttribute((const void*)k_walk,  hipFuncAttributeMaxDynamicSharedMemorySize, WALK2_LDS);

    k_front<<<NB,   1024, FRONT_LDS, stream>>>(z_table, z, convW, convb,
                                               k1W,k1b,q1W,q1b,k2W,k2b,q2W,q2b,
                                               erow, node_i, node_j, wp8, rat, exw, omega);
    k_walk <<<NB*4, 1024, WALK2_LDS, stream>>>(wp8, rat, exw, node_i, node_j, featbuf);
    k_final<<<1,    256,  0,         stream>>>(mW1, mb1, mW2, mb2, featbuf, omega, out);
}

// Round 9
// 216.328 us; speedup vs baseline: 1.0108x; 1.0108x over previous
//
#include <hip/hip_runtime.h>

#define NB 256
#define NPER 128
#define NN 32768
#define DEG 8
#define EREAL (NN*DEG)
#define HH 32
#define NHEADS 2
#define WLEN 7
#define RSQRT_H 0.17677669529663687f

#define FRONT_LDS 136208
#define WALK2_LDS 139520

// swizzled index for [128][128] f32 matrix: row n, elem v.
// float4-chunk q = v>>2 stored at q^(n&31) -> rows coalesced, columns conflict-free.
__device__ __forceinline__ int sidx8(int n, int v){
    return n*128 + ((((v>>2) ^ (n&31))<<2) | (v&3));
}

// ============ K1: fused embed + 3xGCN + QK projections + attention ============
__global__ __launch_bounds__(1024) void k_front(
    const float* __restrict__ z_table, const int* __restrict__ z,
    const float* __restrict__ convW, const float* __restrict__ convb,
    const float* __restrict__ k1W, const float* __restrict__ k1b,
    const float* __restrict__ q1W, const float* __restrict__ q1b,
    const float* __restrict__ k2W, const float* __restrict__ k2b,
    const float* __restrict__ q2W, const float* __restrict__ q2b,
    const int* __restrict__ erow, const int* __restrict__ node_i, const int* __restrict__ node_j,
    float2* __restrict__ wp8, float* __restrict__ rat_g,
    float* __restrict__ exw_g, float* __restrict__ omega_g)
{
    extern __shared__ char sm[];
    float* xl   = (float*)sm;               // [128][32]
    float* t1   = (float*)(sm + 16384);
    float* t2   = (float*)(sm + 32768);
    float* Wb   = (float*)(sm + 49152);     // 4096 floats staging (warr overlay)
    float* rowf = (float*)(sm + 65536);     // [128][64] q-proj (chunk-swizzled)
    float* colf = (float*)(sm + 98304);     // [128][64] k-proj (chunk-swizzled)
    int*   rows = (int*)(sm + 131072);      // [128][8]
    float* dinv = (float*)(sm + 135168);
    float* bias = (float*)(sm + 135680);
    float* omg  = (float*)(sm + 136192);

    int b = blockIdx.x, tid = threadIdx.x;
    int iloc = node_i[b] & 127, jloc = node_j[b] & 127;

    #pragma unroll
    for (int ii=0;ii<4;ii++){
        int i = tid + ii*1024;
        int n = i>>5, d = i&31;
        xl[i] = z_table[z[b*128+n]*32 + d];
    }
    rows[(tid&127)*8 + (tid>>7)] = erow[b*1024 + tid] & 127;
    if (tid < 128) dinv[tid] = rsqrtf((tid==iloc||tid==jloc)? 10.f : 9.f);

    int j = tid & 31, rg = tid>>5;
    for (int l=0;l<3;l++){
        __syncthreads();
        Wb[tid] = convW[l*1024+tid];
        if (tid<32) bias[tid] = convb[l*32+tid];
        __syncthreads();
        float Wc[32];
        #pragma unroll
        for (int k=0;k<32;k++) Wc[k] = Wb[k*32+j];
        #pragma unroll
        for (int ii=0;ii<4;ii++){
            int r = rg + 32*ii;
            const float4* xr = (const float4*)&xl[r*32];
            float a = 0.f;
            #pragma unroll
            for (int k4=0;k4<8;k4++){
                float4 xv = xr[k4];
                a += xv.x*Wc[4*k4] + xv.y*Wc[4*k4+1] + xv.z*Wc[4*k4+2] + xv.w*Wc[4*k4+3];
            }
            t1[r*32+j] = a;
        }
        __syncthreads();
        #pragma unroll
        for (int ii=0;ii<4;ii++){
            int c = rg + 32*ii;
            float acc = dinv[c]*t1[c*32+j];
            #pragma unroll
            for (int s=0;s<8;s++){
                int r = rows[c*8+s];
                acc += dinv[r]*t1[r*32+j];
            }
            if (c==iloc) acc += dinv[jloc]*t1[jloc*32+j];
            if (c==jloc) acc += dinv[iloc]*t1[iloc*32+j];
            float v = dinv[c]*acc + bias[j];
            if (l<2) v = fmaxf(v,0.f);
            xl[c*32+j] = v;
        }
    }
    __syncthreads();
    for (int i=tid;i<2048;i+=1024) Wb[i] = (i<1024)? k1W[i] : q1W[i-1024];
    if (tid<64) bias[tid] = (tid<32)? k1b[tid] : q1b[tid-32];
    __syncthreads();
    {
        float Wa[32], Wq[32];
        #pragma unroll
        for (int k=0;k<32;k++){ Wa[k] = Wb[k*32+j]; Wq[k] = Wb[1024 + k*32+j]; }
        #pragma unroll
        for (int ii=0;ii<4;ii++){
            int n = rg + 32*ii;
            const float4* xr = (const float4*)&xl[n*32];
            float a1 = bias[j], a2 = bias[32+j];
            #pragma unroll
            for (int k4=0;k4<8;k4++){
                float4 xv = xr[k4];
                a1 += xv.x*Wa[4*k4] + xv.y*Wa[4*k4+1] + xv.z*Wa[4*k4+2] + xv.w*Wa[4*k4+3];
                a2 += xv.x*Wq[4*k4] + xv.y*Wq[4*k4+1] + xv.z*Wq[4*k4+2] + xv.w*Wq[4*k4+3];
            }
            t1[n*32+j] = a1>0.f? a1 : 0.2f*a1;
            t2[n*32+j] = a2>0.f? a2 : 0.2f*a2;
        }
    }
    __syncthreads();
    for (int i=tid;i<4096;i+=1024) Wb[i] = (i<2048)? k2W[i] : q2W[i-2048];
    if (tid<128) bias[tid] = (tid<64)? k2b[tid] : q2b[tid-64];
    __syncthreads();
    {
        int j2 = tid & 63, rg2 = tid>>6;
        float Wk[32], Wq[32];
        #pragma unroll
        for (int k=0;k<32;k++){ Wk[k] = Wb[k*64+j2]; Wq[k] = Wb[2048 + k*64+j2]; }
        #pragma unroll
        for (int ii=0;ii<8;ii++){
            int n = rg2 + 16*ii;
            const float4* u4 = (const float4*)&t1[n*32];
            const float4* v4 = (const float4*)&t2[n*32];
            float o1 = bias[j2], o2 = bias[64+j2];
            #pragma unroll
            for (int k4=0;k4<8;k4++){
                float4 u = u4[k4], v = v4[k4];
                o1 += u.x*Wk[4*k4] + u.y*Wk[4*k4+1] + u.z*Wk[4*k4+2] + u.w*Wk[4*k4+3];
                o2 += v.x*Wq[4*k4] + v.y*Wq[4*k4+1] + v.z*Wq[4*k4+2] + v.w*Wq[4*k4+3];
            }
            int sidx = n*64 + ((((j2>>2) ^ (n&7)) << 2) | (j2&3));
            rowf[sidx] = o1;
            colf[sidx] = o2;
        }
    }
    float* warr = Wb;
    __syncthreads();
    {
        int c = tid & 127, h = (tid>>7)&1, sgrp = tid>>8;
        int cs = c&7, h8 = h*8;
        const float4* cf = (const float4*)&colf[c*64];
        float4 kv[8];
        #pragma unroll
        for (int k4=0;k4<8;k4++) kv[k4] = cf[h8 + (k4^cs)];
        #pragma unroll
        for (int si=0;si<2;si++){
            int s = sgrp*2+si;
            int r = rows[c*8+s];
            int rs = r&7;
            const float4* rf = (const float4*)&rowf[r*64];
            float a = 0.f;
            #pragma unroll
            for (int k4=0;k4<8;k4++){
                float4 q = rf[h8 + (k4^rs)];
                a += q.x*kv[k4].x + q.y*kv[k4].y + q.z*kv[k4].z + q.w*kv[k4].w;
            }
            warr[(h*128+c)*9+s] = a*RSQRT_H;
        }
        if (sgrp==0){
            int r = -1;
            if (c==jloc) r = iloc; else if (c==iloc) r = jloc;
            float a = -3.0e38f;
            if (r>=0){
                int rs = r&7;
                const float4* rf = (const float4*)&rowf[r*64];
                a = 0.f;
                #pragma unroll
                for (int k4=0;k4<8;k4++){
                    float4 q = rf[h8 + (k4^rs)];
                    a += q.x*kv[k4].x + q.y*kv[k4].y + q.z*kv[k4].z + q.w*kv[k4].w;
                }
                a *= RSQRT_H;
            }
            warr[(h*128+c)*9+8] = a;
        }
    }
    __syncthreads();
    if (tid < 256){
        int c = tid & 127, h = tid >> 7;
        float wv[9];
        #pragma unroll
        for (int s=0;s<9;s++) wv[s] = warr[(h*128+c)*9+s];
        float wmax = wv[0];
        #pragma unroll
        for (int s=1;s<9;s++) wmax = fmaxf(wmax, wv[s]);
        float e[9]; float sp = 0.f;
        #pragma unroll
        for (int s=0;s<9;s++){ e[s] = expf(wv[s]-wmax); sp += e[s]; }
        float sm_ = sp - e[8];
        float rp = 1.f/(sp+1e-16f);
        float rat = (sp+1e-16f)/(sm_+1e-16f);
        size_t base = ((size_t)h*NN + b*128 + c)*8;
        #pragma unroll
        for (int s=0;s<8;s++)
            wp8[base+s] = make_float2(e[s]*rp, __int_as_float(rows[c*8+s]));  // raw row idx
        rat_g[h*NN + b*128 + c] = rat;
        if (c==jloc || c==iloc){
            int k = (c==jloc)? 0 : 1;
            exw_g[(b*2+h)*2 + k] = e[8]*rp;
            omg[h*2+k] = 1.f/(1.f+expf(-wv[8]));
        }
    }
    __syncthreads();
    if (tid < 2) omega_g[b*2+tid] = omg[tid*2] + omg[tid*2+1];
}

// ============ K2: walk via A^2..A^4 + trace identities, 1 block per (b,h,sg) ============
// SoA weight tables cwT/crT [8][128] (bank = col -> conflict-free for every consumer);
// phase-robust lane->chunk map jj = j8^(c&7) so both consecutive-8 and stride-8
// hardware phasings of b128 span all 8 chunk residues -> conflict-free mults.
__global__ __launch_bounds__(1024) void k_walk(
    const float2* __restrict__ wp8, const float* __restrict__ rat_g,
    const float* __restrict__ exw_g,
    const int* __restrict__ node_i, const int* __restrict__ node_j,
    float* __restrict__ featbuf)
{
    extern __shared__ char sm[];
    float*  PX = (float*)sm;                 // 64KB
    float*  PY = (float*)(sm + 65536);       // 64KB
    float*  cwT= (float*)(sm + 131072);      // [8][128] weights (SoA) 4KB
    int*    crT= (int*)  (sm + 135168);      // [8][128] rows (SoA) 4KB
    float*  scr= (float*)(sm + 139264);      // 64 floats
    int bid = blockIdx.x;
    int b = bid>>2, h = (bid>>1)&1, sg = bid&1;
    int tid = threadIdx.x;

    {   float2 p = wp8[((size_t)h*NN + b*128)*8 + tid];
        if (sg) p.x *= rat_g[h*NN + b*128 + (tid>>3)];
        cwT[(tid&7)*128 + (tid>>3)] = p.x;
        crT[(tid&7)*128 + (tid>>3)] = __float_as_int(p.y);
    }
    int iloc = node_i[b]&127, jloc = node_j[b]&127;
    float exw0=0.f, exw1=0.f; int exc0=-1, exc1=-1;
    if (!sg){
        exw0 = exw_g[(b*2+h)*2+0];
        exw1 = exw_g[(b*2+h)*2+1];
        exc0 = jloc; exc1 = iloc;
    }
    {   float4* PX4 = (float4*)PX;
        #pragma unroll
        for (int k=0;k<4;k++) PX4[tid + k*1024] = make_float4(0.f,0.f,0.f,0.f);
    }
    __syncthreads();
    // ---- build A^1 into PX (waves 1-2; wave 0 freed for column propagation) ----
    if (tid >= 64 && tid < 192){
        int c = tid - 64;
        #pragma unroll
        for (int s=0;s<8;s++){
            float w = cwT[s*128+c];
            int   r = crT[s*128+c];
            PX[sidx8(c, r)] += w;
        }
        if (c==exc0) PX[sidx8(c, iloc)] += exw0;
        if (c==exc1) PX[sidx8(c, jloc)] += exw1;
    }
    // ---- column propagation (wave 0, SoA reads: bank = lane -> free) ----
    if (tid < 64){
        int l = tid;
        float ci0 = (iloc==l)?1.f:0.f, ci1 = (iloc==64+l)?1.f:0.f;
        float cj0 = (jloc==l)?1.f:0.f, cj1 = (jloc==64+l)?1.f:0.f;
        int il = iloc&63, jl = jloc&63;
        for (int t=1;t<=9;t++){
            float a0 = __shfl(ci0, il), a1 = __shfl(ci1, il);
            float b0 = __shfl(cj0, il), b1 = __shfl(cj1, il);
            float c0 = __shfl(ci0, jl), c1 = __shfl(ci1, jl);
            float d0 = __shfl(cj0, jl), d1 = __shfl(cj1, jl);
            float vi_ci = (iloc<64)? a0:a1;   // ci[iloc]
            float vi_cj = (iloc<64)? b0:b1;   // cj[iloc]
            float vj_ci = (jloc<64)? c0:c1;   // ci[jloc]
            float vj_cj = (jloc<64)? d0:d1;   // cj[jloc]
            if (t>=3 && l==0){
                int tt = t-3;
                featbuf[((0*2+sg)*WLEN + tt)*(NHEADS*NB) + h*NB + b] = vi_ci + vj_cj; // nl
                featbuf[((1*2+sg)*WLEN + tt)*(NHEADS*NB) + h*NB + b] = vi_cj + vj_ci; // ll
            }
            if (t<=8){
                float nci0=0.f,ncj0=0.f,nci1=0.f,ncj1=0.f;
                #pragma unroll
                for (int s=0;s<8;s++){
                    float w0 = cwT[s*128+l];   int r0 = crT[s*128+l];
                    float xlo = __shfl(ci0, r0&63), xhi = __shfl(ci1, r0&63);
                    float ylo = __shfl(cj0, r0&63), yhi = __shfl(cj1, r0&63);
                    nci0 += w0 * ((r0<64)? xlo:xhi);
                    ncj0 += w0 * ((r0<64)? ylo:yhi);
                    float w1 = cwT[s*128+64+l]; int r1 = crT[s*128+64+l];
                    xlo = __shfl(ci0, r1&63); xhi = __shfl(ci1, r1&63);
                    ylo = __shfl(cj0, r1&63); yhi = __shfl(cj1, r1&63);
                    nci1 += w1 * ((r1<64)? xlo:xhi);
                    ncj1 += w1 * ((r1<64)? ylo:yhi);
                }
                if (exc0==l)    { nci0 += exw0*vi_ci; ncj0 += exw0*vi_cj; }
                if (exc0==64+l) { nci1 += exw0*vi_ci; ncj1 += exw0*vi_cj; }
                if (exc1==l)    { nci0 += exw1*vj_ci; ncj0 += exw1*vj_cj; }
                if (exc1==64+l) { nci1 += exw1*vj_ci; ncj1 += exw1*vj_cj; }
                ci0=nci0; ci1=nci1; cj0=ncj0; cj1=ncj1;
            }
        }
    }
    __syncthreads();

    int c = tid>>3, j8 = tid&7, cx = c&31;
    int jj = j8 ^ (c&7);                 // phase-robust chunk base
    auto mult = [&](float* dst, const float* src){
        float4 a0={0,0,0,0}, a1={0,0,0,0}, a2={0,0,0,0}, a3={0,0,0,0};
        #pragma unroll
        for (int s=0;s<8;s++){
            float w = cwT[s*128+c];
            int   r = crT[s*128+c];
            const float4* srow = (const float4*)src + r*32;
            int rx = r&31;
            float4 v0=srow[(jj+ 0)^rx], v1=srow[(jj+ 8)^rx], v2=srow[(jj+16)^rx], v3=srow[(jj+24)^rx];
            a0.x+=w*v0.x; a0.y+=w*v0.y; a0.z+=w*v0.z; a0.w+=w*v0.w;
            a1.x+=w*v1.x; a1.y+=w*v1.y; a1.z+=w*v1.z; a1.w+=w*v1.w;
            a2.x+=w*v2.x; a2.y+=w*v2.y; a2.z+=w*v2.z; a2.w+=w*v2.w;
            a3.x+=w*v3.x; a3.y+=w*v3.y; a3.z+=w*v3.z; a3.w+=w*v3.w;
        }
        if (c==exc0){
            const float4* srow = (const float4*)src + iloc*32; int rx = iloc&31;
            float4 v0=srow[(jj+ 0)^rx], v1=srow[(jj+ 8)^rx], v2=srow[(jj+16)^rx], v3=srow[(jj+24)^rx];
            a0.x+=exw0*v0.x; a0.y+=exw0*v0.y; a0.z+=exw0*v0.z; a0.w+=exw0*v0.w;
            a1.x+=exw0*v1.x; a1.y+=exw0*v1.y; a1.z+=exw0*v1.z; a1.w+=exw0*v1.w;
            a2.x+=exw0*v2.x; a2.y+=exw0*v2.y; a2.z+=exw0*v2.z; a2.w+=exw0*v2.w;
            a3.x+=exw0*v3.x; a3.y+=exw0*v3.y; a3.z+=exw0*v3.z; a3.w+=exw0*v3.w;
        }
        if (c==exc1){
            const float4* srow = (const float4*)src + jloc*32; int rx = jloc&31;
            float4 v0=srow[(jj+ 0)^rx], v1=srow[(jj+ 8)^rx], v2=srow[(jj+16)^rx], v3=srow[(jj+24)^rx];
            a0.x+=exw1*v0.x; a0.y+=exw1*v0.y; a0.z+=exw1*v0.z; a0.w+=exw1*v0.w;
            a1.x+=exw1*v1.x; a1.y+=exw1*v1.y; a1.z+=exw1*v1.z; a1.w+=exw1*v1.w;
            a2.x+=exw1*v2.x; a2.y+=exw1*v2.y; a2.z+=exw1*v2.z; a2.w+=exw1*v2.w;
            a3.x+=exw1*v3.x; a3.y+=exw1*v3.y; a3.z+=exw1*v3.z; a3.w+=exw1*v3.w;
        }
        float4* drow = (float4*)dst + c*32;
        drow[(jj+ 0)^cx]=a0; drow[(jj+ 8)^cx]=a1; drow[(jj+16)^cx]=a2; drow[(jj+24)^cx]=a3;
    };
    auto wreduce = [](float v){
        #pragma unroll
        for (int o=32;o;o>>=1) v += __shfl_down(v,o);
        return v;
    };

    mult(PY, PX);                       // A^2
    __syncthreads();
    mult(PX, PY);                       // A^3 (overwrites A^1)
    if (tid<128){                       // tr2 = diag(A^2) concurrent (reads PY only)
        float d = wreduce(PY[sidx8(tid,tid)]);
        if ((tid&63)==0) scr[0+(tid>>6)] = d;
    }
    __syncthreads();
    mult(PY, PX);                       // A^4 (overwrites A^2)
    if (tid<128){                       // tr3 = diag(A^3)
        float d = wreduce(PX[sidx8(tid,tid)]);
        if ((tid&63)==0) scr[2+(tid>>6)] = d;
    }
    __syncthreads();
    // ---- tr4 diag, tr5 sparse, tr6/7/8 transpose pairs ----
    if (tid<128){
        float d = wreduce(PY[sidx8(tid,tid)]);
        if ((tid&63)==0) scr[4+(tid>>6)] = d;
        float s5 = 0.f;
        #pragma unroll
        for (int s=0;s<8;s++){
            float w = cwT[s*128+tid];
            int   r = crT[s*128+tid];
            s5 += w * PY[sidx8(r, tid)];
        }
        if (tid==exc0) s5 += exw0 * PY[sidx8(iloc, jloc)];
        if (tid==exc1) s5 += exw1 * PY[sidx8(jloc, iloc)];
        s5 = wreduce(s5);
        if ((tid&63)==0) scr[6+(tid>>6)] = s5;
    }
    {   // pair phase: lane j8 owns elements bb = j8+8m (2 lanes/bank both sides)
        float t6=0.f, t7=0.f, t8=0.f;
        #pragma unroll
        for (int m=0;m<16;m++){
            int bb = j8 + 8*m;
            int ai = sidx8(c, bb);
            int bi = sidx8(bb, c);
            float a3 = PX[ai], a4 = PY[ai];
            float b3 = PX[bi], b4 = PY[bi];
            t6 += a3*b3; t7 += a3*b4; t8 += a4*b4;
        }
        t6 = wreduce(t6); t7 = wreduce(t7); t8 = wreduce(t8);
        int w = tid>>6;
        if ((tid&63)==0){ scr[8+w]=t6; scr[24+w]=t7; scr[40+w]=t8; }
    }
    __syncthreads();
    if (tid==0){
        float tr2=scr[0]+scr[1], tr3=scr[2]+scr[3], tr4=scr[4]+scr[5], tr5=scr[6]+scr[7];
        float t6=0.f,t7=0.f,t8=0.f;
        #pragma unroll
        for (int w=0;w<16;w++){ t6+=scr[8+w]; t7+=scr[24+w]; t8+=scr[40+w]; }
        int gb = ((2*2+sg)*WLEN)*(NHEADS*NB) + h*NB + b;
        featbuf[gb+0*(NHEADS*NB)] = tr2;
        featbuf[gb+1*(NHEADS*NB)] = tr3;
        featbuf[gb+2*(NHEADS*NB)] = tr4;
        featbuf[gb+3*(NHEADS*NB)] = tr5;
        featbuf[gb+4*(NHEADS*NB)] = t6;
        featbuf[gb+5*(NHEADS*NB)] = t7;
        featbuf[gb+6*(NHEADS*NB)] = t8;
    }
}

// ============ K3: feature assembly + MLP ============
__global__ __launch_bounds__(256) void k_final(const float* __restrict__ W1, const float* __restrict__ b1,
                       const float* __restrict__ W2, const float* __restrict__ b2,
                       const float* __restrict__ featbuf, const float* __restrict__ omega,
                       float* __restrict__ out){
    __shared__ float sW1[72*HH];
    __shared__ float sb1[HH];
    __shared__ float sW2[HH];
    __shared__ float sb2;
    int tid = threadIdx.x;
    for (int i=tid;i<72*HH;i+=256) sW1[i] = W1[i];
    if (tid<HH){ sb1[tid]=b1[tid]; sW2[tid]=W2[tid]; }
    if (tid==0) sb2 = b2[0];
    __syncthreads();
    int b = tid;
    float h1[HH];
    #pragma unroll
    for (int j2=0;j2<HH;j2++) h1[j2] = sb1[j2];
    auto rd = [&](int idx){ return featbuf[idx]; };
    auto addf = [&](int fi, float v){
        #pragma unroll
        for (int j2=0;j2<HH;j2++) h1[j2] += v * sW1[fi*HH + j2];
    };
    for (int h2=0;h2<NHEADS;h2++)
        for (int t=0;t<WLEN;t++){
            float gp = rd(((2*2+0)*WLEN+t)*(NHEADS*NB)+h2*NB+b);
            float gm = rd(((2*2+1)*WLEN+t)*(NHEADS*NB)+h2*NB+b);
            addf(h2*WLEN+t, gp-gm);
        }
    for (int h2=0;h2<NHEADS;h2++) addf(14+h2, omega[b*NHEADS+h2]);
    for (int h2=0;h2<NHEADS;h2++)
        for (int t=0;t<WLEN;t++){
            addf(16+h2*WLEN+t, rd(((0*2+0)*WLEN+t)*(NHEADS*NB)+h2*NB+b));
            addf(30+h2*WLEN+t, rd(((0*2+1)*WLEN+t)*(NHEADS*NB)+h2*NB+b));
            addf(44+h2*WLEN+t, rd(((1*2+0)*WLEN+t)*(NHEADS*NB)+h2*NB+b));
            addf(58+h2*WLEN+t, rd(((1*2+1)*WLEN+t)*(NHEADS*NB)+h2*NB+b));
        }
    float o = sb2;
    #pragma unroll
    for (int j2=0;j2<HH;j2++) o += fmaxf(h1[j2],0.f)*sW2[j2];
    out[b] = o;
}

extern "C" void kernel_launch(void* const* d_in, const int* in_sizes, int n_in,
                              void* d_out, int out_size, void* d_ws, size_t ws_size,
                              hipStream_t stream){
    const float* z_table = (const float*)d_in[0];
    const float* convW   = (const float*)d_in[1];
    const float* convb   = (const float*)d_in[2];
    const float* k1W     = (const float*)d_in[3];
    const float* k1b     = (const float*)d_in[4];
    const float* q1W     = (const float*)d_in[5];
    const float* q1b     = (const float*)d_in[6];
    const float* k2W     = (const float*)d_in[7];
    const float* k2b     = (const float*)d_in[8];
    const float* q2W     = (const float*)d_in[9];
    const float* q2b     = (const float*)d_in[10];
    const float* mW1     = (const float*)d_in[11];
    const float* mb1     = (const float*)d_in[12];
    const float* mW2     = (const float*)d_in[13];
    const float* mb2     = (const float*)d_in[14];
    const int* z         = (const int*)d_in[15];
    const int* erow      = (const int*)d_in[16];
    const int* node_i    = (const int*)d_in[20];
    const int* node_j    = (const int*)d_in[21];
    float* out = (float*)d_out;

    char* ws = (char*)d_ws;
    size_t off = 0;
    auto alloc = [&](size_t bytes){ void* p = ws + off; off += (bytes + 255) & ~255ULL; return p; };
    float2* wp8     = (float2*)alloc((size_t)NHEADS*NN*8*8);
    float*  rat     = (float*) alloc((size_t)NHEADS*NN*4);
    float*  exw     = (float*) alloc((size_t)NB*NHEADS*2*4);
    float*  omega   = (float*) alloc((size_t)NB*NHEADS*4);
    float*  featbuf = (float*) alloc((size_t)3*2*WLEN*NHEADS*NB*4);

    hipFuncSetAttribute((const void*)k_front, hipFuncAttributeMaxDynamicSharedMemorySize, FRONT_LDS);
    hipFuncSetAttribute((const void*)k_walk,  hipFuncAttributeMaxDynamicSharedMemorySize, WALK2_LDS);

    k_front<<<NB,   1024, FRONT_LDS, stream>>>(z_table, z, convW, convb,
                                               k1W,k1b,q1W,q1b,k2W,k2b,q2W,q2b,
                                               erow, node_i, node_j, wp8, rat, exw, omega);
    k_walk <<<NB*4, 1024, WALK2_LDS, stream>>>(wp8, rat, exw, node_i, node_j, featbuf);
    k_final<<<1,    256,  0,         stream>>>(mW1, mb1, mW2, mb2, featbuf, omega, out);
}

// Round 10
// 209.474 us; speedup vs baseline: 1.0439x; 1.0327x over previous
//
#include <hip/hip_runtime.h>

#define NB 256
#define NPER 128
#define NN 32768
#define DEG 8
#define EREAL (NN*DEG)
#define HH 32
#define NHEADS 2
#define WLEN 7
#define RSQRT_H 0.17677669529663687f

#define FRONT_LDS 136208
#define WALK3_LDS 73984

// swizzled index for [128][128] f32 matrix: row n, elem v.
// float4-chunk q = v>>2 stored at q^(n&31) -> rows coalesced, columns conflict-free.
__device__ __forceinline__ int sidx8(int n, int v){
    return n*128 + ((((v>>2) ^ (n&31))<<2) | (v&3));
}

// ============ K1: fused embed + 3xGCN + QK projections + attention ============
__global__ __launch_bounds__(1024) void k_front(
    const float* __restrict__ z_table, const int* __restrict__ z,
    const float* __restrict__ convW, const float* __restrict__ convb,
    const float* __restrict__ k1W, const float* __restrict__ k1b,
    const float* __restrict__ q1W, const float* __restrict__ q1b,
    const float* __restrict__ k2W, const float* __restrict__ k2b,
    const float* __restrict__ q2W, const float* __restrict__ q2b,
    const int* __restrict__ erow, const int* __restrict__ node_i, const int* __restrict__ node_j,
    float2* __restrict__ wp8, float* __restrict__ rat_g,
    float* __restrict__ exw_g, float* __restrict__ omega_g)
{
    extern __shared__ char sm[];
    float* xl   = (float*)sm;               // [128][32]
    float* t1   = (float*)(sm + 16384);
    float* t2   = (float*)(sm + 32768);
    float* Wb   = (float*)(sm + 49152);     // 4096 floats staging (warr overlay)
    float* rowf = (float*)(sm + 65536);     // [128][64] q-proj (chunk-swizzled)
    float* colf = (float*)(sm + 98304);     // [128][64] k-proj (chunk-swizzled)
    int*   rows = (int*)(sm + 131072);      // [128][8]
    float* dinv = (float*)(sm + 135168);
    float* bias = (float*)(sm + 135680);
    float* omg  = (float*)(sm + 136192);

    int b = blockIdx.x, tid = threadIdx.x;
    int iloc = node_i[b] & 127, jloc = node_j[b] & 127;

    #pragma unroll
    for (int ii=0;ii<4;ii++){
        int i = tid + ii*1024;
        int n = i>>5, d = i&31;
        xl[i] = z_table[z[b*128+n]*32 + d];
    }
    rows[(tid&127)*8 + (tid>>7)] = erow[b*1024 + tid] & 127;
    if (tid < 128) dinv[tid] = rsqrtf((tid==iloc||tid==jloc)? 10.f : 9.f);

    int j = tid & 31, rg = tid>>5;
    for (int l=0;l<3;l++){
        __syncthreads();
        Wb[tid] = convW[l*1024+tid];
        if (tid<32) bias[tid] = convb[l*32+tid];
        __syncthreads();
        float Wc[32];
        #pragma unroll
        for (int k=0;k<32;k++) Wc[k] = Wb[k*32+j];
        #pragma unroll
        for (int ii=0;ii<4;ii++){
            int r = rg + 32*ii;
            const float4* xr = (const float4*)&xl[r*32];
            float a = 0.f;
            #pragma unroll
            for (int k4=0;k4<8;k4++){
                float4 xv = xr[k4];
                a += xv.x*Wc[4*k4] + xv.y*Wc[4*k4+1] + xv.z*Wc[4*k4+2] + xv.w*Wc[4*k4+3];
            }
            t1[r*32+j] = a;
        }
        __syncthreads();
        #pragma unroll
        for (int ii=0;ii<4;ii++){
            int c = rg + 32*ii;
            float acc = dinv[c]*t1[c*32+j];
            #pragma unroll
            for (int s=0;s<8;s++){
                int r = rows[c*8+s];
                acc += dinv[r]*t1[r*32+j];
            }
            if (c==iloc) acc += dinv[jloc]*t1[jloc*32+j];
            if (c==jloc) acc += dinv[iloc]*t1[iloc*32+j];
            float v = dinv[c]*acc + bias[j];
            if (l<2) v = fmaxf(v,0.f);
            xl[c*32+j] = v;
        }
    }
    __syncthreads();
    for (int i=tid;i<2048;i+=1024) Wb[i] = (i<1024)? k1W[i] : q1W[i-1024];
    if (tid<64) bias[tid] = (tid<32)? k1b[tid] : q1b[tid-32];
    __syncthreads();
    {
        float Wa[32], Wq[32];
        #pragma unroll
        for (int k=0;k<32;k++){ Wa[k] = Wb[k*32+j]; Wq[k] = Wb[1024 + k*32+j]; }
        #pragma unroll
        for (int ii=0;ii<4;ii++){
            int n = rg + 32*ii;
            const float4* xr = (const float4*)&xl[n*32];
            float a1 = bias[j], a2 = bias[32+j];
            #pragma unroll
            for (int k4=0;k4<8;k4++){
                float4 xv = xr[k4];
                a1 += xv.x*Wa[4*k4] + xv.y*Wa[4*k4+1] + xv.z*Wa[4*k4+2] + xv.w*Wa[4*k4+3];
                a2 += xv.x*Wq[4*k4] + xv.y*Wq[4*k4+1] + xv.z*Wq[4*k4+2] + xv.w*Wq[4*k4+3];
            }
            t1[n*32+j] = a1>0.f? a1 : 0.2f*a1;
            t2[n*32+j] = a2>0.f? a2 : 0.2f*a2;
        }
    }
    __syncthreads();
    for (int i=tid;i<4096;i+=1024) Wb[i] = (i<2048)? k2W[i] : q2W[i-2048];
    if (tid<128) bias[tid] = (tid<64)? k2b[tid] : q2b[tid-64];
    __syncthreads();
    {
        int j2 = tid & 63, rg2 = tid>>6;
        float Wk[32], Wq[32];
        #pragma unroll
        for (int k=0;k<32;k++){ Wk[k] = Wb[k*64+j2]; Wq[k] = Wb[2048 + k*64+j2]; }
        #pragma unroll
        for (int ii=0;ii<8;ii++){
            int n = rg2 + 16*ii;
            const float4* u4 = (const float4*)&t1[n*32];
            const float4* v4 = (const float4*)&t2[n*32];
            float o1 = bias[j2], o2 = bias[64+j2];
            #pragma unroll
            for (int k4=0;k4<8;k4++){
                float4 u = u4[k4], v = v4[k4];
                o1 += u.x*Wk[4*k4] + u.y*Wk[4*k4+1] + u.z*Wk[4*k4+2] + u.w*Wk[4*k4+3];
                o2 += v.x*Wq[4*k4] + v.y*Wq[4*k4+1] + v.z*Wq[4*k4+2] + v.w*Wq[4*k4+3];
            }
            int sidx = n*64 + ((((j2>>2) ^ (n&7)) << 2) | (j2&3));
            rowf[sidx] = o1;
            colf[sidx] = o2;
        }
    }
    float* warr = Wb;
    __syncthreads();
    {
        int c = tid & 127, h = (tid>>7)&1, sgrp = tid>>8;
        int cs = c&7, h8 = h*8;
        const float4* cf = (const float4*)&colf[c*64];
        float4 kv[8];
        #pragma unroll
        for (int k4=0;k4<8;k4++) kv[k4] = cf[h8 + (k4^cs)];
        #pragma unroll
        for (int si=0;si<2;si++){
            int s = sgrp*2+si;
            int r = rows[c*8+s];
            int rs = r&7;
            const float4* rf = (const float4*)&rowf[r*64];
            float a = 0.f;
            #pragma unroll
            for (int k4=0;k4<8;k4++){
                float4 q = rf[h8 + (k4^rs)];
                a += q.x*kv[k4].x + q.y*kv[k4].y + q.z*kv[k4].z + q.w*kv[k4].w;
            }
            warr[(h*128+c)*9+s] = a*RSQRT_H;
        }
        if (sgrp==0){
            int r = -1;
            if (c==jloc) r = iloc; else if (c==iloc) r = jloc;
            float a = -3.0e38f;
            if (r>=0){
                int rs = r&7;
                const float4* rf = (const float4*)&rowf[r*64];
                a = 0.f;
                #pragma unroll
                for (int k4=0;k4<8;k4++){
                    float4 q = rf[h8 + (k4^rs)];
                    a += q.x*kv[k4].x + q.y*kv[k4].y + q.z*kv[k4].z + q.w*kv[k4].w;
                }
                a *= RSQRT_H;
            }
            warr[(h*128+c)*9+8] = a;
        }
    }
    __syncthreads();
    if (tid < 256){
        int c = tid & 127, h = tid >> 7;
        float wv[9];
        #pragma unroll
        for (int s=0;s<9;s++) wv[s] = warr[(h*128+c)*9+s];
        float wmax = wv[0];
        #pragma unroll
        for (int s=1;s<9;s++) wmax = fmaxf(wmax, wv[s]);
        float e[9]; float sp = 0.f;
        #pragma unroll
        for (int s=0;s<9;s++){ e[s] = expf(wv[s]-wmax); sp += e[s]; }
        float sm_ = sp - e[8];
        float rp = 1.f/(sp+1e-16f);
        float rat = (sp+1e-16f)/(sm_+1e-16f);
        size_t base = ((size_t)h*NN + b*128 + c)*8;
        #pragma unroll
        for (int s=0;s<8;s++)
            wp8[base+s] = make_float2(e[s]*rp, __int_as_float(rows[c*8+s]));  // raw row idx
        rat_g[h*NN + b*128 + c] = rat;
        if (c==jloc || c==iloc){
            int k = (c==jloc)? 0 : 1;
            exw_g[(b*2+h)*2 + k] = e[8]*rp;
            omg[h*2+k] = 1.f/(1.f+expf(-wv[8]));
        }
    }
    __syncthreads();
    if (tid < 2) omega_g[b*2+tid] = omg[tid*2] + omg[tid*2+1];
}

// ============ K2: walk, in-place single buffer, 2 blocks/CU ============
// State A^t lives in ONE 64KB buffer; each mult accumulates A^{t+1} into 4 float4
// registers, barriers, writes back in place. Trace identities sequenced so A^3
// pairs (tr6) and reg-A4 x LDS-A3 (tr7) happen before A^4 overwrites A^3.
__global__ __launch_bounds__(1024, 8) void k_walk(
    const float2* __restrict__ wp8, const float* __restrict__ rat_g,
    const float* __restrict__ exw_g,
    const int* __restrict__ node_i, const int* __restrict__ node_j,
    float* __restrict__ featbuf)
{
    extern __shared__ char sm[];
    float*  PM = (float*)sm;                 // 64KB single state buffer
    float*  cwT= (float*)(sm + 65536);       // [8][128] weights (SoA)
    int*    crT= (int*)  (sm + 69632);       // [8][128] rows (SoA)
    float*  scr= (float*)(sm + 73728);       // 64 floats
    int bid = blockIdx.x;
    int b = bid>>2, h = (bid>>1)&1, sg = bid&1;
    int tid = threadIdx.x;

    {   float2 p = wp8[((size_t)h*NN + b*128)*8 + tid];
        if (sg) p.x *= rat_g[h*NN + b*128 + (tid>>3)];
        cwT[(tid&7)*128 + (tid>>3)] = p.x;
        crT[(tid&7)*128 + (tid>>3)] = __float_as_int(p.y);
    }
    int iloc = node_i[b]&127, jloc = node_j[b]&127;
    float exw0=0.f, exw1=0.f; int exc0=-1, exc1=-1;
    if (!sg){
        exw0 = exw_g[(b*2+h)*2+0];
        exw1 = exw_g[(b*2+h)*2+1];
        exc0 = jloc; exc1 = iloc;
    }
    {   float4* PM4 = (float4*)PM;
        #pragma unroll
        for (int k=0;k<4;k++) PM4[tid + k*1024] = make_float4(0.f,0.f,0.f,0.f);
    }
    __syncthreads();
    // ---- build A^1 into PM (waves 1-2; wave 0 freed for column propagation) ----
    if (tid >= 64 && tid < 192){
        int c = tid - 64;
        #pragma unroll
        for (int s=0;s<8;s++){
            float w = cwT[s*128+c];
            int   r = crT[s*128+c];
            PM[sidx8(c, r)] += w;
        }
        if (c==exc0) PM[sidx8(c, iloc)] += exw0;
        if (c==exc1) PM[sidx8(c, jloc)] += exw1;
    }
    // ---- column propagation (wave 0, SoA reads: bank = lane -> free) ----
    if (tid < 64){
        int l = tid;
        float ci0 = (iloc==l)?1.f:0.f, ci1 = (iloc==64+l)?1.f:0.f;
        float cj0 = (jloc==l)?1.f:0.f, cj1 = (jloc==64+l)?1.f:0.f;
        int il = iloc&63, jl = jloc&63;
        for (int t=1;t<=9;t++){
            float a0 = __shfl(ci0, il), a1 = __shfl(ci1, il);
            float b0 = __shfl(cj0, il), b1 = __shfl(cj1, il);
            float c0 = __shfl(ci0, jl), c1 = __shfl(ci1, jl);
            float d0 = __shfl(cj0, jl), d1 = __shfl(cj1, jl);
            float vi_ci = (iloc<64)? a0:a1;
            float vi_cj = (iloc<64)? b0:b1;
            float vj_ci = (jloc<64)? c0:c1;
            float vj_cj = (jloc<64)? d0:d1;
            if (t>=3 && l==0){
                int tt = t-3;
                featbuf[((0*2+sg)*WLEN + tt)*(NHEADS*NB) + h*NB + b] = vi_ci + vj_cj; // nl
                featbuf[((1*2+sg)*WLEN + tt)*(NHEADS*NB) + h*NB + b] = vi_cj + vj_ci; // ll
            }
            if (t<=8){
                float nci0=0.f,ncj0=0.f,nci1=0.f,ncj1=0.f;
                #pragma unroll
                for (int s=0;s<8;s++){
                    float w0 = cwT[s*128+l];   int r0 = crT[s*128+l];
                    float xlo = __shfl(ci0, r0&63), xhi = __shfl(ci1, r0&63);
                    float ylo = __shfl(cj0, r0&63), yhi = __shfl(cj1, r0&63);
                    nci0 += w0 * ((r0<64)? xlo:xhi);
                    ncj0 += w0 * ((r0<64)? ylo:yhi);
                    float w1 = cwT[s*128+64+l]; int r1 = crT[s*128+64+l];
                    xlo = __shfl(ci0, r1&63); xhi = __shfl(ci1, r1&63);
                    ylo = __shfl(cj0, r1&63); yhi = __shfl(cj1, r1&63);
                    nci1 += w1 * ((r1<64)? xlo:xhi);
                    ncj1 += w1 * ((r1<64)? ylo:yhi);
                }
                if (exc0==l)    { nci0 += exw0*vi_ci; ncj0 += exw0*vi_cj; }
                if (exc0==64+l) { nci1 += exw0*vi_ci; ncj1 += exw0*vi_cj; }
                if (exc1==l)    { nci0 += exw1*vj_ci; ncj0 += exw1*vj_cj; }
                if (exc1==64+l) { nci1 += exw1*vj_ci; ncj1 += exw1*vj_cj; }
                ci0=nci0; ci1=nci1; cj0=ncj0; cj1=ncj1;
            }
        }
    }
    __syncthreads();

    int c = tid>>3, j8 = tid&7, cx = c&31;
    int jj = j8 ^ (c&7);
    float4 a0,a1,a2,a3;
    // read-accumulate next power from PM into registers
    auto macc = [&](){
        a0=make_float4(0,0,0,0); a1=a0; a2=a0; a3=a0;
        #pragma unroll
        for (int s=0;s<8;s++){
            float w = cwT[s*128+c];
            int   r = crT[s*128+c];
            const float4* srow = (const float4*)PM + r*32;
            int rx = r&31;
            float4 v0=srow[(jj+ 0)^rx], v1=srow[(jj+ 8)^rx], v2=srow[(jj+16)^rx], v3=srow[(jj+24)^rx];
            a0.x+=w*v0.x; a0.y+=w*v0.y; a0.z+=w*v0.z; a0.w+=w*v0.w;
            a1.x+=w*v1.x; a1.y+=w*v1.y; a1.z+=w*v1.z; a1.w+=w*v1.w;
            a2.x+=w*v2.x; a2.y+=w*v2.y; a2.z+=w*v2.z; a2.w+=w*v2.w;
            a3.x+=w*v3.x; a3.y+=w*v3.y; a3.z+=w*v3.z; a3.w+=w*v3.w;
        }
        if (c==exc0){
            const float4* srow = (const float4*)PM + iloc*32; int rx = iloc&31;
            float4 v0=srow[(jj+ 0)^rx], v1=srow[(jj+ 8)^rx], v2=srow[(jj+16)^rx], v3=srow[(jj+24)^rx];
            a0.x+=exw0*v0.x; a0.y+=exw0*v0.y; a0.z+=exw0*v0.z; a0.w+=exw0*v0.w;
            a1.x+=exw0*v1.x; a1.y+=exw0*v1.y; a1.z+=exw0*v1.z; a1.w+=exw0*v1.w;
            a2.x+=exw0*v2.x; a2.y+=exw0*v2.y; a2.z+=exw0*v2.z; a2.w+=exw0*v2.w;
            a3.x+=exw0*v3.x; a3.y+=exw0*v3.y; a3.z+=exw0*v3.z; a3.w+=exw0*v3.w;
        }
        if (c==exc1){
            const float4* srow = (const float4*)PM + jloc*32; int rx = jloc&31;
            float4 v0=srow[(jj+ 0)^rx], v1=srow[(jj+ 8)^rx], v2=srow[(jj+16)^rx], v3=srow[(jj+24)^rx];
            a0.x+=exw1*v0.x; a0.y+=exw1*v0.y; a0.z+=exw1*v0.z; a0.w+=exw1*v0.w;
            a1.x+=exw1*v1.x; a1.y+=exw1*v1.y; a1.z+=exw1*v1.z; a1.w+=exw1*v1.w;
            a2.x+=exw1*v2.x; a2.y+=exw1*v2.y; a2.z+=exw1*v2.z; a2.w+=exw1*v2.w;
            a3.x+=exw1*v3.x; a3.y+=exw1*v3.y; a3.z+=exw1*v3.z; a3.w+=exw1*v3.w;
        }
    };
    auto wrt = [&](){
        float4* drow = (float4*)PM + c*32;
        drow[(jj+ 0)^cx]=a0; drow[(jj+ 8)^cx]=a1; drow[(jj+16)^cx]=a2; drow[(jj+24)^cx]=a3;
    };
    auto wreduce = [](float v){
        #pragma unroll
        for (int o=32;o;o>>=1) v += __shfl_down(v,o);
        return v;
    };
    int w = tid>>6;

    // A^2
    macc();
    __syncthreads();
    wrt();
    __syncthreads();
    // A^3 reads (PM=A2) + tr2 diag(A2)
    macc();
    if (tid<128){
        float d = wreduce(PM[sidx8(tid,tid)]);
        if ((tid&63)==0) scr[0+(tid>>6)] = d;
    }
    __syncthreads();
    wrt();
    __syncthreads();
    // A^4 reads (PM=A3) + tr3 diag + tr6 pairs + tr7 (regs x A3^T)
    macc();
    if (tid<128){
        float d = wreduce(PM[sidx8(tid,tid)]);
        if ((tid&63)==0) scr[2+(tid>>6)] = d;
    }
    {
        float t6=0.f;
        #pragma unroll
        for (int m=0;m<16;m++){
            int bb = j8 + 8*m;
            t6 += PM[sidx8(c, bb)] * PM[sidx8(bb, c)];
        }
        t6 = wreduce(t6);
        if ((tid&63)==0) scr[8+w] = t6;
    }
    {
        float t7=0.f;
        #pragma unroll
        for (int e=0;e<4;e++){
            t7 += ((const float*)&a0)[e] * PM[sidx8(4*(jj   )+e, c)];
            t7 += ((const float*)&a1)[e] * PM[sidx8(4*(jj+ 8)+e, c)];
            t7 += ((const float*)&a2)[e] * PM[sidx8(4*(jj+16)+e, c)];
            t7 += ((const float*)&a3)[e] * PM[sidx8(4*(jj+24)+e, c)];
        }
        t7 = wreduce(t7);
        if ((tid&63)==0) scr[24+w] = t7;
    }
    __syncthreads();
    wrt();                               // PM = A^4
    __syncthreads();
    // tr4 diag + tr5 sparse + tr8 pairs (PM=A4)
    if (tid<128){
        float d = wreduce(PM[sidx8(tid,tid)]);
        if ((tid&63)==0) scr[4+(tid>>6)] = d;
        float s5 = 0.f;
        #pragma unroll
        for (int s=0;s<8;s++){
            float ww = cwT[s*128+tid];
            int   r  = crT[s*128+tid];
            s5 += ww * PM[sidx8(r, tid)];
        }
        if (tid==exc0) s5 += exw0 * PM[sidx8(iloc, jloc)];
        if (tid==exc1) s5 += exw1 * PM[sidx8(jloc, iloc)];
        s5 = wreduce(s5);
        if ((tid&63)==0) scr[6+(tid>>6)] = s5;
    }
    {
        float t8=0.f;
        #pragma unroll
        for (int m=0;m<16;m++){
            int bb = j8 + 8*m;
            t8 += PM[sidx8(c, bb)] * PM[sidx8(bb, c)];
        }
        t8 = wreduce(t8);
        if ((tid&63)==0) scr[40+w] = t8;
    }
    __syncthreads();
    if (tid==0){
        float tr2=scr[0]+scr[1], tr3=scr[2]+scr[3], tr4=scr[4]+scr[5], tr5=scr[6]+scr[7];
        float t6=0.f,t7=0.f,t8=0.f;
        #pragma unroll
        for (int k=0;k<16;k++){ t6+=scr[8+k]; t7+=scr[24+k]; t8+=scr[40+k]; }
        int gb = ((2*2+sg)*WLEN)*(NHEADS*NB) + h*NB + b;
        featbuf[gb+0*(NHEADS*NB)] = tr2;
        featbuf[gb+1*(NHEADS*NB)] = tr3;
        featbuf[gb+2*(NHEADS*NB)] = tr4;
        featbuf[gb+3*(NHEADS*NB)] = tr5;
        featbuf[gb+4*(NHEADS*NB)] = t6;
        featbuf[gb+5*(NHEADS*NB)] = t7;
        featbuf[gb+6*(NHEADS*NB)] = t8;
    }
}

// ============ K3: feature assembly + MLP ============
__global__ __launch_bounds__(256) void k_final(const float* __restrict__ W1, const float* __restrict__ b1,
                       const float* __restrict__ W2, const float* __restrict__ b2,
                       const float* __restrict__ featbuf, const float* __restrict__ omega,
                       float* __restrict__ out){
    __shared__ float sW1[72*HH];
    __shared__ float sb1[HH];
    __shared__ float sW2[HH];
    __shared__ float sb2;
    int tid = threadIdx.x;
    for (int i=tid;i<72*HH;i+=256) sW1[i] = W1[i];
    if (tid<HH){ sb1[tid]=b1[tid]; sW2[tid]=W2[tid]; }
    if (tid==0) sb2 = b2[0];
    __syncthreads();
    int b = tid;
    float h1[HH];
    #pragma unroll
    for (int j2=0;j2<HH;j2++) h1[j2] = sb1[j2];
    auto rd = [&](int idx){ return featbuf[idx]; };
    auto addf = [&](int fi, float v){
        #pragma unroll
        for (int j2=0;j2<HH;j2++) h1[j2] += v * sW1[fi*HH + j2];
    };
    for (int h2=0;h2<NHEADS;h2++)
        for (int t=0;t<WLEN;t++){
            float gp = rd(((2*2+0)*WLEN+t)*(NHEADS*NB)+h2*NB+b);
            float gm = rd(((2*2+1)*WLEN+t)*(NHEADS*NB)+h2*NB+b);
            addf(h2*WLEN+t, gp-gm);
        }
    for (int h2=0;h2<NHEADS;h2++) addf(14+h2, omega[b*NHEADS+h2]);
    for (int h2=0;h2<NHEADS;h2++)
        for (int t=0;t<WLEN;t++){
            addf(16+h2*WLEN+t, rd(((0*2+0)*WLEN+t)*(NHEADS*NB)+h2*NB+b));
            addf(30+h2*WLEN+t, rd(((0*2+1)*WLEN+t)*(NHEADS*NB)+h2*NB+b));
            addf(44+h2*WLEN+t, rd(((1*2+0)*WLEN+t)*(NHEADS*NB)+h2*NB+b));
            addf(58+h2*WLEN+t, rd(((1*2+1)*WLEN+t)*(NHEADS*NB)+h2*NB+b));
        }
    float o = sb2;
    #pragma unroll
    for (int j2=0;j2<HH;j2++) o += fmaxf(h1[j2],0.f)*sW2[j2];
    out[b] = o;
}

extern "C" void kernel_launch(void* const* d_in, const int* in_sizes, int n_in,
                              void* d_out, int out_size, void* d_ws, size_t ws_size,
                              hipStream_t stream){
    const float* z_table = (const float*)d_in[0];
    const float* convW   = (const float*)d_in[1];
    const float* convb   = (const float*)d_in[2];
    const float* k1W     = (const float*)d_in[3];
    const float* k1b     = (const float*)d_in[4];
    const float* q1W     = (const float*)d_in[5];
    const float* q1b     = (const float*)d_in[6];
    const float* k2W     = (const float*)d_in[7];
    const float* k2b     = (const float*)d_in[8];
    const float* q2W     = (const float*)d_in[9];
    const float* q2b     = (const float*)d_in[10];
    const float* mW1     = (const float*)d_in[11];
    const float* mb1     = (const float*)d_in[12];
    const float* mW2     = (const float*)d_in[13];
    const float* mb2     = (const float*)d_in[14];
    const int* z         = (const int*)d_in[15];
    const int* erow      = (const int*)d_in[16];
    const int* node_i    = (const int*)d_in[20];
    const int* node_j    = (const int*)d_in[21];
    float* out = (float*)d_out;

    char* ws = (char*)d_ws;
    size_t off = 0;
    auto alloc = [&](size_t bytes){ void* p = ws + off; off += (bytes + 255) & ~255ULL; return p; };
    float2* wp8     = (float2*)alloc((size_t)NHEADS*NN*8*8);
    float*  rat     = (float*) alloc((size_t)NHEADS*NN*4);
    float*  exw     = (float*) alloc((size_t)NB*NHEADS*2*4);
    float*  omega   = (float*) alloc((size_t)NB*NHEADS*4);
    float*  featbuf = (float*) alloc((size_t)3*2*WLEN*NHEADS*NB*4);

    hipFuncSetAttribute((const void*)k_front, hipFuncAttributeMaxDynamicSharedMemorySize, FRONT_LDS);
    hipFuncSetAttribute((const void*)k_walk,  hipFuncAttributeMaxDynamicSharedMemorySize, WALK3_LDS);

    k_front<<<NB,   1024, FRONT_LDS, stream>>>(z_table, z, convW, convb,
                                               k1W,k1b,q1W,q1b,k2W,k2b,q2W,q2b,
                                               erow, node_i, node_j, wp8, rat, exw, omega);
    k_walk <<<NB*4, 1024, WALK3_LDS, stream>>>(wp8, rat, exw, node_i, node_j, featbuf);
    k_final<<<1,    256,  0,         stream>>>(mW1, mb1, mW2, mb2, featbuf, omega, out);
}